// Round 4
// baseline (143.334 us; speedup 1.0000x reference)
//
#include <hip/hip_runtime.h>

// CosineAttention collapses to a linear map:
//   out[q] = (q_hat @ M + u) / (q_hat . s + n)
// with per-(b,h) moments over masked keys:
//   M[j][d] = sum_k m_k khat[k][j] V[k][d]   (64x64)
//   s[j]    = sum_k m_k khat[k][j]
//   u[d]    = sum_k m_k V[k][d]
//   n       = sum_k m_k
//
// R4: outer-product (k_moments) and matvec (k_out) moved to MFMA
// 16x16x32 bf16 with hi/lo split (3 MFMAs per product term pair).
// Verified layouts: A[m=lane&15][k=quad*8+j], B[k=quad*8+j][n=lane&15],
// C/D row=quad*4+reg, col=lane&15.

#define S 4096
#define D 64
#define BH 16            // B*H = 2*8
#define FSTRIDE 4352     // per-(b,h) moment stride in floats
#define NE 4225          // 4096 (M) + 64 (s) + 64 (u) + 1 (n)
#define NCH 64           // chunks per head (64 rows per block)
#define PADW 65          // LDS row stride (floats), breaks bank conflicts

typedef __attribute__((ext_vector_type(8))) short short8;
typedef __attribute__((ext_vector_type(4))) float f32x4;

__device__ __forceinline__ float rl(float v, int l) {
    return __int_as_float(__builtin_amdgcn_readlane(__float_as_int(v), l));
}
__device__ __forceinline__ unsigned short bf16h(float x) {
    unsigned u = __float_as_uint(x);
    u += 0x7FFF + ((u >> 16) & 1);          // round-nearest-even
    return (unsigned short)(u >> 16);
}
__device__ __forceinline__ float bf16f(unsigned short h) {
    return __uint_as_float(((unsigned)h) << 16);
}
__device__ __forceinline__ void split2(float x, short& hi, short& lo) {
    unsigned short h = bf16h(x);
    hi = (short)h;
    lo = (short)bf16h(x - bf16f(h));
}

// ---------------- kernel 1: per-chunk partial moments via MFMA ----------
// grid (BH, NCH), block 256 (4 waves); each wave contracts its 16 rows.
__global__ __launch_bounds__(256) void k_moments(
    const float* __restrict__ K, const float* __restrict__ V,
    const int* __restrict__ mask, float* __restrict__ part)
{
    __shared__ float sm[2 * 4 * 16 * PADW];   // K-staging | V-staging
    __shared__ float redsu[129];
    float* red = sm;                           // 4096 floats, aliases K-staging

    const int bh    = blockIdx.x;
    const int chunk = blockIdx.y;
    const int lane  = threadIdx.x & 63;
    const int wave  = threadIdx.x >> 6;
    const int quad  = lane >> 4;
    const int l15   = lane & 15;
    const int row0  = chunk * 64;

    const float* Kh = K + (size_t)bh * S * D;
    const float* Vh = V + (size_t)bh * S * D;
    const int*   mb = mask + (bh >> 3) * S;    // mask [B,1,1,S], H=8

    // phase A: lane = block-row (duplicated across waves), fp32 norms
    const int rowL = row0 + lane;
    const float mL = (float)mb[rowL];
    float ss = 0.f;
    {
        const float4* kp = (const float4*)(Kh + (size_t)rowL * D);
        #pragma unroll
        for (int d4 = 0; d4 < 16; ++d4) {
            float4 kv = kp[d4];
            ss = fmaf(kv.x, kv.x, ss);
            ss = fmaf(kv.y, kv.y, ss);
            ss = fmaf(kv.z, kv.z, ss);
            ss = fmaf(kv.w, kv.w, ss);
        }
    }
    const float minvL = mL / fmaxf(sqrtf(ss), 1e-12f);   // masked -> 0

    // stage kh, vm for this wave's 16 rows (coalesced loads, lane = d)
    float* Kst = sm + wave * (16 * PADW);
    float* Vst = sm + 4 * (16 * PADW) + wave * (16 * PADW);
    float s_acc = 0.f, u_acc = 0.f, n_acc = 0.f;
    #pragma unroll
    for (int r = 0; r < 16; ++r) {
        const int src = wave * 16 + r;
        const int row = row0 + src;
        float kd = Kh[(size_t)row * D + lane];
        float vd = Vh[(size_t)row * D + lane];
        float aj = rl(minvL, src);
        float mj = rl(mL, src);
        float kh = kd * aj;
        float vm = vd * mj;
        s_acc += kh; u_acc += vm; n_acc += mj;
        Kst[r * PADW + lane] = kh;
        Vst[r * PADW + lane] = vm;
    }
    __syncthreads();

    // A fragments: A[m=j][k=row], rows 0..15 valid (quads 2,3 zero-pad)
    short8 ahi[4], alo[4];
    #pragma unroll
    for (int tm = 0; tm < 4; ++tm) {
        #pragma unroll
        for (int jj = 0; jj < 8; ++jj) {
            float x = (quad < 2) ? Kst[(quad * 8 + jj) * PADW + tm * 16 + l15] : 0.f;
            short h, l; split2(x, h, l);
            ahi[tm][jj] = h; alo[tm][jj] = l;
        }
    }
    f32x4 acc[4][4];
    #pragma unroll
    for (int tm = 0; tm < 4; ++tm)
        #pragma unroll
        for (int tn = 0; tn < 4; ++tn)
            acc[tm][tn] = (f32x4){0.f, 0.f, 0.f, 0.f};

    #pragma unroll
    for (int tn = 0; tn < 4; ++tn) {
        short8 bhi, blo;
        #pragma unroll
        for (int jj = 0; jj < 8; ++jj) {
            float x = (quad < 2) ? Vst[(quad * 8 + jj) * PADW + tn * 16 + l15] : 0.f;
            short h, l; split2(x, h, l);
            bhi[jj] = h; blo[jj] = l;
        }
        #pragma unroll
        for (int tm = 0; tm < 4; ++tm) {
            acc[tm][tn] = __builtin_amdgcn_mfma_f32_16x16x32_bf16(alo[tm], bhi, acc[tm][tn], 0, 0, 0);
            acc[tm][tn] = __builtin_amdgcn_mfma_f32_16x16x32_bf16(ahi[tm], blo, acc[tm][tn], 0, 0, 0);
            acc[tm][tn] = __builtin_amdgcn_mfma_f32_16x16x32_bf16(ahi[tm], bhi, acc[tm][tn], 0, 0, 0);
        }
    }
    __syncthreads();   // staging reads done; red alias is now safe

    // cross-wave merge (deterministic). C/D: row=quad*4+rr, col=l15.
    if (wave == 0) {
        #pragma unroll
        for (int tm = 0; tm < 4; ++tm)
            #pragma unroll
            for (int tn = 0; tn < 4; ++tn)
                #pragma unroll
                for (int rr = 0; rr < 4; ++rr)
                    red[(tm * 16 + quad * 4 + rr) * 64 + tn * 16 + l15] = acc[tm][tn][rr];
        redsu[lane] = s_acc;
        redsu[64 + lane] = u_acc;
        if (lane == 0) redsu[128] = n_acc;
    }
    __syncthreads();
    for (int w = 1; w < 4; ++w) {
        if (wave == w) {
            #pragma unroll
            for (int tm = 0; tm < 4; ++tm)
                #pragma unroll
                for (int tn = 0; tn < 4; ++tn)
                    #pragma unroll
                    for (int rr = 0; rr < 4; ++rr)
                        red[(tm * 16 + quad * 4 + rr) * 64 + tn * 16 + l15] += acc[tm][tn][rr];
            redsu[lane] += s_acc;
            redsu[64 + lane] += u_acc;
            if (lane == 0) redsu[128] += n_acc;
        }
        __syncthreads();
    }

    float* pp = part + ((size_t)bh * NCH + chunk) * FSTRIDE;
    for (int i = threadIdx.x; i < NE; i += 256)
        pp[i] = (i < 4096) ? red[i] : redsu[i - 4096];
}

// ---------------- kernel 2: partial reduction (+ emits M^T) -------------
__global__ __launch_bounds__(256) void k_reduce(
    const float* __restrict__ part, float* __restrict__ fin,
    float* __restrict__ finT)
{
    const int bh = blockIdx.x;
    const int e  = blockIdx.y * 256 + threadIdx.x;
    if (e >= NE) return;
    const float* p = part + (size_t)bh * NCH * FSTRIDE + e;
    float a0 = 0.f, a1 = 0.f, a2 = 0.f, a3 = 0.f;
    #pragma unroll
    for (int c = 0; c < NCH; c += 4) {
        a0 += p[(size_t)(c + 0) * FSTRIDE];
        a1 += p[(size_t)(c + 1) * FSTRIDE];
        a2 += p[(size_t)(c + 2) * FSTRIDE];
        a3 += p[(size_t)(c + 3) * FSTRIDE];
    }
    float v = (a0 + a1) + (a2 + a3);
    fin[(size_t)bh * FSTRIDE + e] = v;
    if (e < 4096)                              // e = j*64 + d  ->  M^T[d][j]
        finT[(size_t)bh * 4096 + (e & 63) * 64 + (e >> 6)] = v;
}

// ---------------- kernel 3: out = (qhat M + u) * rden via MFMA ----------
// grid (BH, NCH), block 256; each wave's 16 q-rows are the MFMA M-dim.
__global__ __launch_bounds__(256) void k_out(
    const float* __restrict__ Q, const float* __restrict__ fin,
    const float* __restrict__ finT, float* __restrict__ out)
{
    __shared__ float Qsm[4 * 16 * PADW];
    __shared__ float rden_lds[64];

    const int bh    = blockIdx.x;
    const int chunk = blockIdx.y;
    const int lane  = threadIdx.x & 63;
    const int wave  = threadIdx.x >> 6;
    const int quad  = lane >> 4;
    const int l15   = lane & 15;
    const int row0  = chunk * 64;

    const float* fb  = fin  + (size_t)bh * FSTRIDE;
    const float* fbT = finT + (size_t)bh * 4096;
    const float* Qh  = Q + (size_t)bh * S * D;
    float*       Oh  = out + (size_t)bh * S * D;

    const float sreg = fb[4096 + lane];
    const float nval = fb[4224];
    float u4[4];
    #pragma unroll
    for (int tn = 0; tn < 4; ++tn) u4[tn] = fb[4160 + tn * 16 + l15];

    // phase A: lane = block-row (duplicated across waves)
    const int rowL = row0 + lane;
    float ss = 0.f, qs = 0.f;
    {
        const float4* qp = (const float4*)(Qh + (size_t)rowL * D);
        #pragma unroll
        for (int d4 = 0; d4 < 16; ++d4) {
            float4 qv = qp[d4];
            float s0 = rl(sreg, 4 * d4    );
            float s1 = rl(sreg, 4 * d4 + 1);
            float s2 = rl(sreg, 4 * d4 + 2);
            float s3 = rl(sreg, 4 * d4 + 3);
            ss = fmaf(qv.x, qv.x, ss);
            ss = fmaf(qv.y, qv.y, ss);
            ss = fmaf(qv.z, qv.z, ss);
            ss = fmaf(qv.w, qv.w, ss);
            qs = fmaf(qv.x, s0, qs);
            qs = fmaf(qv.y, s1, qs);
            qs = fmaf(qv.z, s2, qs);
            qs = fmaf(qv.w, s3, qs);
        }
    }
    const float invL  = 1.f / fmaxf(sqrtf(ss), 1e-12f);
    const float rdenL = 1.f / fmaf(qs, invL, nval);
    rden_lds[lane] = rdenL;                    // all waves write same values

    // stage qhat rows (coalesced, lane = d)
    float* Qst = Qsm + wave * (16 * PADW);
    #pragma unroll
    for (int r = 0; r < 16; ++r) {
        const int src = wave * 16 + r;
        Qst[r * PADW + lane] = Qh[(size_t)(row0 + src) * D + lane] * rl(invL, src);
    }
    __syncthreads();

    // A frags: A[m=l15][k=ks*32+quad*8+jj]
    short8 ahi[2], alo[2];
    #pragma unroll
    for (int ks = 0; ks < 2; ++ks)
        #pragma unroll
        for (int jj = 0; jj < 8; ++jj) {
            float x = Qst[l15 * PADW + ks * 32 + quad * 8 + jj];
            short h, l; split2(x, h, l);
            ahi[ks][jj] = h; alo[ks][jj] = l;
        }

    f32x4 acc[4];
    #pragma unroll
    for (int tn = 0; tn < 4; ++tn) acc[tn] = (f32x4){0.f, 0.f, 0.f, 0.f};

    #pragma unroll
    for (int tn = 0; tn < 4; ++tn) {
        #pragma unroll
        for (int ks = 0; ks < 2; ++ks) {
            const float* bp = fbT + (tn * 16 + l15) * 64 + ks * 32 + quad * 8;
            short8 bhi, blo;
            #pragma unroll
            for (int jj = 0; jj < 8; ++jj) {
                float x = bp[jj];                  // contiguous -> dwordx4
                short h, l; split2(x, h, l);
                bhi[jj] = h; blo[jj] = l;
            }
            acc[tn] = __builtin_amdgcn_mfma_f32_16x16x32_bf16(alo[ks], bhi, acc[tn], 0, 0, 0);
            acc[tn] = __builtin_amdgcn_mfma_f32_16x16x32_bf16(ahi[ks], blo, acc[tn], 0, 0, 0);
            acc[tn] = __builtin_amdgcn_mfma_f32_16x16x32_bf16(ahi[ks], bhi, acc[tn], 0, 0, 0);
        }
    }

    // epilogue: C/D row = quad*4+rr (q-row within wave), col = l15
    #pragma unroll
    for (int rr = 0; rr < 4; ++rr) {
        const int lrow = wave * 16 + quad * 4 + rr;
        const float rden = rden_lds[lrow];
        const size_t row = row0 + lrow;
        #pragma unroll
        for (int tn = 0; tn < 4; ++tn)
            Oh[row * D + tn * 16 + l15] = (acc[tn][rr] + u4[tn]) * rden;
    }
}

extern "C" void kernel_launch(void* const* d_in, const int* in_sizes, int n_in,
                              void* d_out, int out_size, void* d_ws, size_t ws_size,
                              hipStream_t stream) {
    const float* Q    = (const float*)d_in[0];
    const float* K    = (const float*)d_in[1];
    const float* V    = (const float*)d_in[2];
    const int*   mask = (const int*)d_in[3];
    float* out = (float*)d_out;
    float* ws  = (float*)d_ws;

    float* fin  = ws;                                   // BH * FSTRIDE
    float* finT = ws + (size_t)BH * FSTRIDE;            // BH * 4096
    float* part = finT + (size_t)BH * 4096;             // BH * NCH * FSTRIDE

    k_moments<<<dim3(BH, NCH), 256, 0, stream>>>(K, V, mask, part);
    k_reduce <<<dim3(BH, (NE + 255) / 256), 256, 0, stream>>>(part, fin, finT);
    k_out    <<<dim3(BH, NCH), 256, 0, stream>>>(Q, fin, finT, out);
}

// Round 5
// 107.941 us; speedup vs baseline: 1.3279x; 1.3279x over previous
//
#include <hip/hip_runtime.h>

// CosineAttention collapses to a linear map:
//   out[q] = (q_hat @ M + u) / (q_hat . s + n)
// with per-(b,h) moments over masked keys:
//   M[j][d] = sum_k m_k khat[k][j] V[k][d]   (64x64)
//   s[j]    = sum_k m_k khat[k][j]   u[d] = sum_k m_k V[k][d]   n = sum_k m_k
//
// R5: pure bf16 MFMA (no hi/lo split; s/u/n + denominator stay fp32 exact),
// K=32 full-utilization fragments via transposed [dim][key] bf16 LDS staging
// (1 ds_read_b128 per fragment, zero unpack), cooperative phase A,
// M^T pre-converted to bf16 once in k_reduce.

#define S 4096
#define D 64
#define BH 16
#define FSTRIDE 4352
#define NE 4225          // 4096 (M) + 64 (s) + 64 (u) + 1 (n)
#define NCHM 32          // k_moments: 128 rows per block
#define NCHO 64          // k_out: 64 rows per block
#define KSTR 40          // KstT/VstT key stride in shorts (32 keys + 8 pad)
#define QSTR 72          // Qst dim stride in shorts (64 dims + 8 pad)

typedef __attribute__((ext_vector_type(8))) short short8;
typedef __attribute__((ext_vector_type(4))) float f32x4;

__device__ __forceinline__ float rl(float v, int l) {
    return __int_as_float(__builtin_amdgcn_readlane(__float_as_int(v), l));
}
__device__ __forceinline__ unsigned bf16h(float x) {
    unsigned u = __float_as_uint(x);
    u += 0x7FFF + ((u >> 16) & 1);          // round-nearest-even
    return u >> 16;
}

// ---------------- kernel 1: partial moments, 128 keys/block --------------
__global__ __launch_bounds__(256) void k_moments(
    const float* __restrict__ K, const float* __restrict__ V,
    const int* __restrict__ mask, float* __restrict__ part)
{
    __shared__ float red[4 * 4096];          // 64 KB; staging aliases first 40 KB
    __shared__ float sured[4 * 132];
    unsigned short* stag = (unsigned short*)red;

    const int bh    = blockIdx.x;
    const int chunk = blockIdx.y;
    const int tid   = threadIdx.x;
    const int lane  = tid & 63;
    const int wave  = tid >> 6;
    const int quad  = lane >> 4;
    const int l15   = lane & 15;
    const int row0  = chunk * 128 + wave * 32;   // this wave's 32 keys

    const float* Kh = K + (size_t)bh * S * D;
    const float* Vh = V + (size_t)bh * S * D;
    const int*   mb = mask + (bh >> 3) * S;      // mask [B,1,1,S], H=8

    // ---- phase A: 2 lanes per row (lane = c*32 + r), 1 shfl hop ----
    const int r32 = lane & 31;
    const int c2  = lane >> 5;
    const int rowA = row0 + r32;
    float ss = 0.f;
    {
        const float4* kp = (const float4*)(Kh + (size_t)rowA * D + c2 * 32);
        #pragma unroll
        for (int i = 0; i < 8; ++i) {
            float4 kv = kp[i];
            ss = fmaf(kv.x, kv.x, ss);
            ss = fmaf(kv.y, kv.y, ss);
            ss = fmaf(kv.z, kv.z, ss);
            ss = fmaf(kv.w, kv.w, ss);
        }
    }
    ss += __shfl_xor(ss, 32, 64);
    const float mval = (float)mb[rowA];
    const float minv = mval / fmaxf(sqrtf(ss), 1e-12f);  // masked -> 0

    // ---- staging: transposed bf16 [dim=lane][key=r]; fp32 s/u/n ----
    unsigned short* KstT = stag + wave * (64 * KSTR);
    unsigned short* VstT = stag + 4 * (64 * KSTR) + wave * (64 * KSTR);
    unsigned* KstW = (unsigned*)KstT;
    unsigned* VstW = (unsigned*)VstT;

    float s_acc = 0.f, u_acc = 0.f, n_acc = 0.f;
    unsigned kprev = 0, vprev = 0;
    #pragma unroll
    for (int r = 0; r < 32; ++r) {
        const int row = row0 + r;
        float kd = Kh[(size_t)row * D + lane];
        float vd = Vh[(size_t)row * D + lane];
        float aj = rl(minv, r);
        float mj = rl(mval, r);
        float kh = kd * aj;
        float vm = vd * mj;
        s_acc += kh; u_acc += vm; n_acc += mj;
        unsigned ku = bf16h(kh), vu = bf16h(vm);
        if (r & 1) {
            KstW[(lane * KSTR + (r - 1)) >> 1] = kprev | (ku << 16);
            VstW[(lane * KSTR + (r - 1)) >> 1] = vprev | (vu << 16);
        } else { kprev = ku; vprev = vu; }
    }
    __syncthreads();

    // ---- fragments: one ds_read_b128 each; MFMA over K=32 keys ----
    short8 af[4], bfr[4];
    #pragma unroll
    for (int t = 0; t < 4; ++t) {
        af[t]  = *(const short8*)(KstT + (t * 16 + l15) * KSTR + quad * 8);
        bfr[t] = *(const short8*)(VstT + (t * 16 + l15) * KSTR + quad * 8);
    }
    f32x4 acc[4][4];
    #pragma unroll
    for (int tm = 0; tm < 4; ++tm)
        #pragma unroll
        for (int tn = 0; tn < 4; ++tn)
            acc[tm][tn] = (f32x4){0.f, 0.f, 0.f, 0.f};
    #pragma unroll
    for (int tn = 0; tn < 4; ++tn)
        #pragma unroll
        for (int tm = 0; tm < 4; ++tm)
            acc[tm][tn] = __builtin_amdgcn_mfma_f32_16x16x32_bf16(
                af[tm], bfr[tn], acc[tm][tn], 0, 0, 0);
    __syncthreads();   // staging reads done; red reuse is safe

    // ---- single-barrier merge: 4 copies, then 4-way sum + store ----
    #pragma unroll
    for (int tm = 0; tm < 4; ++tm)
        #pragma unroll
        for (int tn = 0; tn < 4; ++tn)
            #pragma unroll
            for (int rr = 0; rr < 4; ++rr)
                red[wave * 4096 + (tm * 16 + quad * 4 + rr) * 64 + tn * 16 + l15]
                    = acc[tm][tn][rr];
    sured[wave * 132 + lane]      = s_acc;
    sured[wave * 132 + 64 + lane] = u_acc;
    if (lane == 0) sured[wave * 132 + 128] = n_acc;
    __syncthreads();

    float* pp = part + ((size_t)bh * NCHM + chunk) * FSTRIDE;
    for (int i = tid; i < NE; i += 256) {
        float v;
        if (i < 4096)
            v = red[i] + red[4096 + i] + red[8192 + i] + red[12288 + i];
        else {
            int e = i - 4096;
            v = sured[e] + sured[132 + e] + sured[264 + e] + sured[396 + e];
        }
        pp[i] = v;
    }
}

// ---------------- kernel 2: reduce partials; emit fp32 s/u/n + bf16 M^T --
__global__ __launch_bounds__(256) void k_reduce(
    const float* __restrict__ part, float* __restrict__ fin,
    unsigned short* __restrict__ finTh)
{
    const int bh = blockIdx.x;
    const int e  = blockIdx.y * 256 + threadIdx.x;
    if (e >= NE) return;
    const float* p = part + (size_t)bh * NCHM * FSTRIDE + e;
    float a0 = 0.f, a1 = 0.f, a2 = 0.f, a3 = 0.f;
    #pragma unroll
    for (int c = 0; c < NCHM; c += 4) {
        a0 += p[(size_t)(c + 0) * FSTRIDE];
        a1 += p[(size_t)(c + 1) * FSTRIDE];
        a2 += p[(size_t)(c + 2) * FSTRIDE];
        a3 += p[(size_t)(c + 3) * FSTRIDE];
    }
    float v = (a0 + a1) + (a2 + a3);
    if (e < 4096)   // e = j*64 + d -> M^T[d][j] in bf16
        finTh[(size_t)bh * 4096 + (e & 63) * 64 + (e >> 6)] = (unsigned short)bf16h(v);
    else
        fin[(size_t)bh * FSTRIDE + e] = v;
}

// ---------------- kernel 3: out = (qhat M + u) * rden, barrier-free ------
__global__ __launch_bounds__(256) void k_out(
    const float* __restrict__ Q, const float* __restrict__ fin,
    const unsigned short* __restrict__ finTh, float* __restrict__ out)
{
    __shared__ unsigned short Qst[4 * 16 * QSTR];

    const int bh    = blockIdx.x;
    const int chunk = blockIdx.y;
    const int tid   = threadIdx.x;
    const int lane  = tid & 63;
    const int wave  = tid >> 6;
    const int quad  = lane >> 4;
    const int l15   = lane & 15;
    const int row0  = chunk * 64;

    const float* fb = fin + (size_t)bh * FSTRIDE;
    const unsigned short* fT = finTh + (size_t)bh * 4096;
    const float* Qh = Q + (size_t)bh * S * D;
    float*       Oh = out + (size_t)bh * S * D;

    // ---- phase A: 4 lanes per row (quad = d-chunk); 2 shfl hops ----
    const int rowA = row0 + wave * 16 + l15;
    float ss = 0.f, qs = 0.f;
    {
        const float4* qp = (const float4*)(Qh + (size_t)rowA * D + quad * 16);
        const float4* sp = (const float4*)(fb + 4096 + quad * 16);
        #pragma unroll
        for (int i = 0; i < 4; ++i) {
            float4 qv = qp[i], sv = sp[i];
            ss = fmaf(qv.x, qv.x, ss);
            ss = fmaf(qv.y, qv.y, ss);
            ss = fmaf(qv.z, qv.z, ss);
            ss = fmaf(qv.w, qv.w, ss);
            qs = fmaf(qv.x, sv.x, qs);
            qs = fmaf(qv.y, sv.y, qs);
            qs = fmaf(qv.z, sv.z, qs);
            qs = fmaf(qv.w, sv.w, qs);
        }
    }
    ss += __shfl_xor(ss, 16, 64); ss += __shfl_xor(ss, 32, 64);
    qs += __shfl_xor(qs, 16, 64); qs += __shfl_xor(qs, 32, 64);
    const float nval = fb[4224];
    const float invL = 1.f / fmaxf(sqrtf(ss), 1e-12f);
    const float rden = 1.f / fmaf(qs, invL, nval);   // row wave*16+l15, exact fp32

    // ---- stage qhat bf16 transposed [row][dim] (own-wave region only) ----
    unsigned short* Qw = Qst + wave * 16 * QSTR;
    #pragma unroll
    for (int r = 0; r < 16; ++r) {
        float qd = Qh[(size_t)(row0 + wave * 16 + r) * D + lane];
        Qw[r * QSTR + lane] = (unsigned short)bf16h(qd * rl(invL, r));
    }
    asm volatile("" ::: "memory");   // order ushort stores vs short8 loads

    short8 af0 = *(const short8*)(Qw + l15 * QSTR + quad * 8);
    short8 af1 = *(const short8*)(Qw + l15 * QSTR + 32 + quad * 8);

    f32x4 acc[4];
    #pragma unroll
    for (int tn = 0; tn < 4; ++tn) acc[tn] = (f32x4){0.f, 0.f, 0.f, 0.f};
    #pragma unroll
    for (int tn = 0; tn < 4; ++tn) {
        short8 b0 = *(const short8*)(fT + (tn * 16 + l15) * 64 + quad * 8);
        short8 b1 = *(const short8*)(fT + (tn * 16 + l15) * 64 + 32 + quad * 8);
        acc[tn] = __builtin_amdgcn_mfma_f32_16x16x32_bf16(af0, b0, acc[tn], 0, 0, 0);
        acc[tn] = __builtin_amdgcn_mfma_f32_16x16x32_bf16(af1, b1, acc[tn], 0, 0, 0);
    }

    float u4[4];
    #pragma unroll
    for (int tn = 0; tn < 4; ++tn) u4[tn] = fb[4160 + tn * 16 + l15];

    // epilogue: C/D row = quad*4+rr, col = l15; rden via bpermute
    #pragma unroll
    for (int rr = 0; rr < 4; ++rr) {
        const int src = quad * 4 + rr;
        float rd = __int_as_float(
            __builtin_amdgcn_ds_bpermute(src << 2, __float_as_int(rden)));
        const size_t row = row0 + wave * 16 + src;
        #pragma unroll
        for (int tn = 0; tn < 4; ++tn)
            Oh[row * D + tn * 16 + l15] = (acc[tn][rr] + u4[tn]) * rd;
    }
}

extern "C" void kernel_launch(void* const* d_in, const int* in_sizes, int n_in,
                              void* d_out, int out_size, void* d_ws, size_t ws_size,
                              hipStream_t stream) {
    const float* Q    = (const float*)d_in[0];
    const float* K    = (const float*)d_in[1];
    const float* V    = (const float*)d_in[2];
    const int*   mask = (const int*)d_in[3];
    float* out = (float*)d_out;
    float* ws  = (float*)d_ws;

    float*          fin   = ws;                                      // BH*FSTRIDE f32
    unsigned short* finTh = (unsigned short*)(ws + (size_t)BH * FSTRIDE);  // BH*4096 bf16
    float*          part  = (float*)((char*)finTh + (size_t)BH * 4096 * 2);

    k_moments<<<dim3(BH, NCHM), 256, 0, stream>>>(K, V, mask, part);
    k_reduce <<<dim3(BH, (NE + 255) / 256), 256, 0, stream>>>(part, fin, finTh);
    k_out    <<<dim3(BH, NCHO), 256, 0, stream>>>(Q, fin, finTh, out);
}

// Round 6
// 107.828 us; speedup vs baseline: 1.3293x; 1.0010x over previous
//
#include <hip/hip_runtime.h>

// CosineAttention collapses to a linear map:
//   out[q] = (q_hat @ M + u) / (q_hat . s + n)
// with per-(b,h) moments over masked keys:
//   M[j][d] = sum_k m_k khat[k][j] V[k][d]   (64x64)
//   s[j]    = sum_k m_k khat[k][j]   u[d] = sum_k m_k V[k][d]   n = sum_k m_k
//
// R6: k_moments occupancy 2->4 blocks/CU (LDS 66->38 KB via KSTR=36 +
// pairwise merge aliasing staging), float4 global loads with bpermute
// per-key scales. k_out / k_reduce unchanged from R5 (near their floors).

#define S 4096
#define D 64
#define BH 16
#define FSTRIDE 4352
#define NE 4225          // 4096 (M) + 64 (s) + 64 (u) + 1 (n)
#define NCHM 32          // k_moments: 128 keys per block
#define NCHO 64          // k_out: 64 rows per block
#define KSTR 36          // staging dim-row stride in shorts (32 keys + 4 pad)
#define QSTR 72          // k_out Qst dim stride in shorts

typedef __attribute__((ext_vector_type(8))) short short8;
typedef __attribute__((ext_vector_type(4))) short short4v;
typedef __attribute__((ext_vector_type(4))) float f32x4;

__device__ __forceinline__ float rl(float v, int l) {
    return __int_as_float(__builtin_amdgcn_readlane(__float_as_int(v), l));
}
__device__ __forceinline__ float bperm(float v, int srclane) {
    return __int_as_float(
        __builtin_amdgcn_ds_bpermute(srclane << 2, __float_as_int(v)));
}
__device__ __forceinline__ unsigned bf16h(float x) {
    unsigned u = __float_as_uint(x);
    u += 0x7FFF + ((u >> 16) & 1);          // round-nearest-even
    return u >> 16;
}

// ---------------- kernel 1: partial moments, 128 keys/block --------------
__global__ __launch_bounds__(256, 4) void k_moments(
    const float* __restrict__ K, const float* __restrict__ V,
    const int* __restrict__ mask, float* __restrict__ part)
{
    __shared__ unsigned short stag[8 * 64 * KSTR];   // 36864 B (K | V, 4 waves)
    __shared__ float sured[4 * 132];                 // 2112 B
    float* red0 = (float*)stag;                      // merge aliases staging
    float* red1 = red0 + 4096;

    const int bh    = blockIdx.x;
    const int chunk = blockIdx.y;
    const int tid   = threadIdx.x;
    const int lane  = tid & 63;
    const int wave  = tid >> 6;
    const int quad  = lane >> 4;
    const int l15   = lane & 15;
    const int row0  = chunk * 128 + wave * 32;       // this wave's 32 keys

    const float* Kh = K + (size_t)bh * S * D;
    const float* Vh = V + (size_t)bh * S * D;
    const int*   mb = mask + (bh >> 3) * S;          // mask [B,1,1,S], H=8

    // ---- phase A: 2 lanes per key (lane = c2*32 + r32), 1 shfl hop ----
    const int r32 = lane & 31;
    const int c2  = lane >> 5;
    const int rowA = row0 + r32;
    float ss = 0.f;
    {
        const float4* kp = (const float4*)(Kh + (size_t)rowA * D + c2 * 32);
        #pragma unroll
        for (int i = 0; i < 8; ++i) {
            float4 kv = kp[i];
            ss = fmaf(kv.x, kv.x, ss);
            ss = fmaf(kv.y, kv.y, ss);
            ss = fmaf(kv.z, kv.z, ss);
            ss = fmaf(kv.w, kv.w, ss);
        }
    }
    ss += __shfl_xor(ss, 32, 64);
    const float mval = (float)mb[rowA];
    const float minv = mval / fmaxf(sqrtf(ss), 1e-12f);  // masked -> 0
    // wave key-count (each key's m held by 2 lanes): n = wave_sum(mval)/2
    float nw = mval;
    nw += __shfl_xor(nw, 1, 64);  nw += __shfl_xor(nw, 2, 64);
    nw += __shfl_xor(nw, 4, 64);  nw += __shfl_xor(nw, 8, 64);
    nw += __shfl_xor(nw, 16, 64); nw += __shfl_xor(nw, 32, 64);

    // ---- staging: float4 loads; lane covers dims 4*l15..+3, key 8*quad+i --
    unsigned short* Kst = stag + wave * (64 * KSTR);
    unsigned short* Vst = stag + 4 * (64 * KSTR) + wave * (64 * KSTR);
    unsigned* KstW = (unsigned*)Kst;
    unsigned* VstW = (unsigned*)Vst;

    float4 s4 = {0.f, 0.f, 0.f, 0.f}, u4 = {0.f, 0.f, 0.f, 0.f};
    unsigned kprev[4], vprev[4];
    #pragma unroll
    for (int i = 0; i < 8; ++i) {
        const int key = 8 * quad + i;
        const int row = row0 + key;
        float4 kf = *(const float4*)(Kh + (size_t)row * D + 4 * l15);
        float4 vf = *(const float4*)(Vh + (size_t)row * D + 4 * l15);
        float aj = bperm(minv, key);
        float mj = bperm(mval, key);
        float k0 = kf.x * aj, k1 = kf.y * aj, k2 = kf.z * aj, k3 = kf.w * aj;
        float v0 = vf.x * mj, v1 = vf.y * mj, v2 = vf.z * mj, v3 = vf.w * mj;
        s4.x += k0; s4.y += k1; s4.z += k2; s4.w += k3;
        u4.x += v0; u4.y += v1; u4.z += v2; u4.w += v3;
        unsigned kb0 = bf16h(k0), kb1 = bf16h(k1), kb2 = bf16h(k2), kb3 = bf16h(k3);
        unsigned vb0 = bf16h(v0), vb1 = bf16h(v1), vb2 = bf16h(v2), vb3 = bf16h(v3);
        if (i & 1) {    // write key pair (i-1, i) as one dword per dim
            const int base = 4 * quad + (i >> 1);        // dword within dim row
            KstW[(4 * l15 + 0) * 18 + base] = kprev[0] | (kb0 << 16);
            KstW[(4 * l15 + 1) * 18 + base] = kprev[1] | (kb1 << 16);
            KstW[(4 * l15 + 2) * 18 + base] = kprev[2] | (kb2 << 16);
            KstW[(4 * l15 + 3) * 18 + base] = kprev[3] | (kb3 << 16);
            VstW[(4 * l15 + 0) * 18 + base] = vprev[0] | (vb0 << 16);
            VstW[(4 * l15 + 1) * 18 + base] = vprev[1] | (vb1 << 16);
            VstW[(4 * l15 + 2) * 18 + base] = vprev[2] | (vb2 << 16);
            VstW[(4 * l15 + 3) * 18 + base] = vprev[3] | (vb3 << 16);
        } else {
            kprev[0] = kb0; kprev[1] = kb1; kprev[2] = kb2; kprev[3] = kb3;
            vprev[0] = vb0; vprev[1] = vb1; vprev[2] = vb2; vprev[3] = vb3;
        }
    }
    // fold s/u across quads (2 hops); lanes quad==0 hold dims 4*l15..+3
    s4.x += __shfl_xor(s4.x, 16, 64); s4.x += __shfl_xor(s4.x, 32, 64);
    s4.y += __shfl_xor(s4.y, 16, 64); s4.y += __shfl_xor(s4.y, 32, 64);
    s4.z += __shfl_xor(s4.z, 16, 64); s4.z += __shfl_xor(s4.z, 32, 64);
    s4.w += __shfl_xor(s4.w, 16, 64); s4.w += __shfl_xor(s4.w, 32, 64);
    u4.x += __shfl_xor(u4.x, 16, 64); u4.x += __shfl_xor(u4.x, 32, 64);
    u4.y += __shfl_xor(u4.y, 16, 64); u4.y += __shfl_xor(u4.y, 32, 64);
    u4.z += __shfl_xor(u4.z, 16, 64); u4.z += __shfl_xor(u4.z, 32, 64);
    u4.w += __shfl_xor(u4.w, 16, 64); u4.w += __shfl_xor(u4.w, 32, 64);
    if (quad == 0) {
        sured[wave * 132 + 4 * l15 + 0]      = s4.x;
        sured[wave * 132 + 4 * l15 + 1]      = s4.y;
        sured[wave * 132 + 4 * l15 + 2]      = s4.z;
        sured[wave * 132 + 4 * l15 + 3]      = s4.w;
        sured[wave * 132 + 64 + 4 * l15 + 0] = u4.x;
        sured[wave * 132 + 64 + 4 * l15 + 1] = u4.y;
        sured[wave * 132 + 64 + 4 * l15 + 2] = u4.z;
        sured[wave * 132 + 64 + 4 * l15 + 3] = u4.w;
    }
    if (lane == 0) sured[wave * 132 + 128] = nw * 0.5f;
    __syncthreads();

    // ---- fragments: 2x ds_read_b64 each; MFMA over K=32 keys ----
    short8 af[4], bfr[4];
    #pragma unroll
    for (int t = 0; t < 4; ++t) {
        const unsigned short* ab = Kst + (t * 16 + l15) * KSTR + quad * 8;
        short4v a0 = *(const short4v*)ab;
        short4v a1 = *(const short4v*)(ab + 4);
        af[t] = __builtin_shufflevector(a0, a1, 0, 1, 2, 3, 4, 5, 6, 7);
        const unsigned short* bb = Vst + (t * 16 + l15) * KSTR + quad * 8;
        short4v b0 = *(const short4v*)bb;
        short4v b1 = *(const short4v*)(bb + 4);
        bfr[t] = __builtin_shufflevector(b0, b1, 0, 1, 2, 3, 4, 5, 6, 7);
    }
    f32x4 acc[4][4];
    #pragma unroll
    for (int tm = 0; tm < 4; ++tm)
        #pragma unroll
        for (int tn = 0; tn < 4; ++tn)
            acc[tm][tn] = (f32x4){0.f, 0.f, 0.f, 0.f};
    #pragma unroll
    for (int tn = 0; tn < 4; ++tn)
        #pragma unroll
        for (int tm = 0; tm < 4; ++tm)
            acc[tm][tn] = __builtin_amdgcn_mfma_f32_16x16x32_bf16(
                af[tm], bfr[tn], acc[tm][tn], 0, 0, 0);
    __syncthreads();   // all frag reads done; staging may be overwritten

    // ---- pairwise merge aliasing staging: 0/1 write, 2/3 add ----
    if (wave < 2) {
        float* rd = wave ? red1 : red0;
        #pragma unroll
        for (int tm = 0; tm < 4; ++tm)
            #pragma unroll
            for (int tn = 0; tn < 4; ++tn)
                #pragma unroll
                for (int rr = 0; rr < 4; ++rr)
                    rd[(tm * 16 + quad * 4 + rr) * 64 + tn * 16 + l15]
                        = acc[tm][tn][rr];
    }
    __syncthreads();
    if (wave >= 2) {
        float* rd = (wave == 3) ? red1 : red0;
        #pragma unroll
        for (int tm = 0; tm < 4; ++tm)
            #pragma unroll
            for (int tn = 0; tn < 4; ++tn)
                #pragma unroll
                for (int rr = 0; rr < 4; ++rr)
                    rd[(tm * 16 + quad * 4 + rr) * 64 + tn * 16 + l15]
                        += acc[tm][tn][rr];
    }
    __syncthreads();

    float* pp = part + ((size_t)bh * NCHM + chunk) * FSTRIDE;
    for (int i = tid; i < NE; i += 256) {
        float v;
        if (i < 4096)
            v = red0[i] + red1[i];
        else {
            int e = i - 4096;
            v = sured[e] + sured[132 + e] + sured[264 + e] + sured[396 + e];
        }
        pp[i] = v;
    }
}

// ---------------- kernel 2: reduce partials; emit fp32 s/u/n + bf16 M^T --
__global__ __launch_bounds__(256) void k_reduce(
    const float* __restrict__ part, float* __restrict__ fin,
    unsigned short* __restrict__ finTh)
{
    const int bh = blockIdx.x;
    const int e  = blockIdx.y * 256 + threadIdx.x;
    if (e >= NE) return;
    const float* p = part + (size_t)bh * NCHM * FSTRIDE + e;
    float a0 = 0.f, a1 = 0.f, a2 = 0.f, a3 = 0.f;
    #pragma unroll
    for (int c = 0; c < NCHM; c += 4) {
        a0 += p[(size_t)(c + 0) * FSTRIDE];
        a1 += p[(size_t)(c + 1) * FSTRIDE];
        a2 += p[(size_t)(c + 2) * FSTRIDE];
        a3 += p[(size_t)(c + 3) * FSTRIDE];
    }
    float v = (a0 + a1) + (a2 + a3);
    if (e < 4096)   // e = j*64 + d -> M^T[d][j] in bf16
        finTh[(size_t)bh * 4096 + (e & 63) * 64 + (e >> 6)] = (unsigned short)bf16h(v);
    else
        fin[(size_t)bh * FSTRIDE + e] = v;
}

// ---------------- kernel 3: out = (qhat M + u) * rden, barrier-free ------
__global__ __launch_bounds__(256) void k_out(
    const float* __restrict__ Q, const float* __restrict__ fin,
    const unsigned short* __restrict__ finTh, float* __restrict__ out)
{
    __shared__ unsigned short Qst[4 * 16 * QSTR];

    const int bh    = blockIdx.x;
    const int chunk = blockIdx.y;
    const int tid   = threadIdx.x;
    const int lane  = tid & 63;
    const int wave  = tid >> 6;
    const int quad  = lane >> 4;
    const int l15   = lane & 15;
    const int row0  = chunk * 64;

    const float* fb = fin + (size_t)bh * FSTRIDE;
    const unsigned short* fT = finTh + (size_t)bh * 4096;
    const float* Qh = Q + (size_t)bh * S * D;
    float*       Oh = out + (size_t)bh * S * D;

    // ---- phase A: 4 lanes per row (quad = d-chunk); 2 shfl hops ----
    const int rowA = row0 + wave * 16 + l15;
    float ss = 0.f, qs = 0.f;
    {
        const float4* qp = (const float4*)(Qh + (size_t)rowA * D + quad * 16);
        const float4* sp = (const float4*)(fb + 4096 + quad * 16);
        #pragma unroll
        for (int i = 0; i < 4; ++i) {
            float4 qv = qp[i], sv = sp[i];
            ss = fmaf(qv.x, qv.x, ss);
            ss = fmaf(qv.y, qv.y, ss);
            ss = fmaf(qv.z, qv.z, ss);
            ss = fmaf(qv.w, qv.w, ss);
            qs = fmaf(qv.x, sv.x, qs);
            qs = fmaf(qv.y, sv.y, qs);
            qs = fmaf(qv.z, sv.z, qs);
            qs = fmaf(qv.w, sv.w, qs);
        }
    }
    ss += __shfl_xor(ss, 16, 64); ss += __shfl_xor(ss, 32, 64);
    qs += __shfl_xor(qs, 16, 64); qs += __shfl_xor(qs, 32, 64);
    const float nval = fb[4224];
    const float invL = 1.f / fmaxf(sqrtf(ss), 1e-12f);
    const float rden = 1.f / fmaf(qs, invL, nval);   // row wave*16+l15, exact fp32

    // ---- stage qhat bf16 [row][dim] (own-wave region only) ----
    unsigned short* Qw = Qst + wave * 16 * QSTR;
    #pragma unroll
    for (int r = 0; r < 16; ++r) {
        float qd = Qh[(size_t)(row0 + wave * 16 + r) * D + lane];
        Qw[r * QSTR + lane] = (unsigned short)bf16h(qd * rl(invL, r));
    }
    asm volatile("" ::: "memory");   // order ushort stores vs short8 loads

    short8 af0 = *(const short8*)(Qw + l15 * QSTR + quad * 8);
    short8 af1 = *(const short8*)(Qw + l15 * QSTR + 32 + quad * 8);

    f32x4 acc[4];
    #pragma unroll
    for (int tn = 0; tn < 4; ++tn) acc[tn] = (f32x4){0.f, 0.f, 0.f, 0.f};
    #pragma unroll
    for (int tn = 0; tn < 4; ++tn) {
        short8 b0 = *(const short8*)(fT + (tn * 16 + l15) * 64 + quad * 8);
        short8 b1 = *(const short8*)(fT + (tn * 16 + l15) * 64 + 32 + quad * 8);
        acc[tn] = __builtin_amdgcn_mfma_f32_16x16x32_bf16(af0, b0, acc[tn], 0, 0, 0);
        acc[tn] = __builtin_amdgcn_mfma_f32_16x16x32_bf16(af1, b1, acc[tn], 0, 0, 0);
    }

    float u4[4];
    #pragma unroll
    for (int tn = 0; tn < 4; ++tn) u4[tn] = fb[4160 + tn * 16 + l15];

    // epilogue: C/D row = quad*4+rr, col = l15; rden via bpermute
    #pragma unroll
    for (int rr = 0; rr < 4; ++rr) {
        const int src = quad * 4 + rr;
        float rd = bperm(rden, src);
        const size_t row = row0 + wave * 16 + src;
        #pragma unroll
        for (int tn = 0; tn < 4; ++tn)
            Oh[row * D + tn * 16 + l15] = (acc[tn][rr] + u4[tn]) * rd;
    }
}

extern "C" void kernel_launch(void* const* d_in, const int* in_sizes, int n_in,
                              void* d_out, int out_size, void* d_ws, size_t ws_size,
                              hipStream_t stream) {
    const float* Q    = (const float*)d_in[0];
    const float* K    = (const float*)d_in[1];
    const float* V    = (const float*)d_in[2];
    const int*   mask = (const int*)d_in[3];
    float* out = (float*)d_out;
    float* ws  = (float*)d_ws;

    float*          fin   = ws;                                           // BH*FSTRIDE f32
    unsigned short* finTh = (unsigned short*)(ws + (size_t)BH * FSTRIDE); // BH*4096 bf16
    float*          part  = (float*)((char*)finTh + (size_t)BH * 4096 * 2);

    k_moments<<<dim3(BH, NCHM), 256, 0, stream>>>(K, V, mask, part);
    k_reduce <<<dim3(BH, (NE + 255) / 256), 256, 0, stream>>>(part, fin, finTh);
    k_out    <<<dim3(BH, NCHO), 256, 0, stream>>>(Q, fin, finTh, out);
}